// Round 2
// baseline (187.848 us; speedup 1.0000x reference)
//
#include <hip/hip_runtime.h>
#include <math.h>

#define A_W 200.0f
#define B_BATCH 16
#define N_PTS 65536
#define C_CLS 5

#define STAT_BLOCKS 1024   // 64 blocks per batch, 1024 points each, 4 pts/thread
#define NLL_BLOCKS 1024    // 1024 elements each, 4 elems/thread
#define TPB 256
#define GRID_BLOCKS (STAT_BLOCKS + NLL_BLOCKS)

// ws float layout (zeroed by hipMemsetAsync each launch):
//  [0 .. 255]    stat accumulators: b*16 + v
//                v order: gc0..3, pc0..3, gz0..3, pz0..3 (summed over 64 chunks via atomics)
//  [256 .. 575]  NLL accumulators: 256 + v*32 + (nb & 31)
//                v: 0..4 = nll sums s0..s4, 5..9 = counts c0..c4 (32-way slotted to cap contention)
//  [576]         completion counter (int)
#define ACC_NLL 256
#define ACC_CNT 576
#define ACC_BYTES ((ACC_CNT + 1) * 4)

__device__ inline float wave_reduce_f(float v) {
#pragma unroll
    for (int off = 32; off > 0; off >>= 1)
        v += __shfl_down(v, off, 64);
    return v;
}

__global__ __launch_bounds__(TPB)
void main_kernel(const float* __restrict__ pred,
                 const int* __restrict__ target,
                 const float* __restrict__ points,
                 const float* __restrict__ prev,
                 const unsigned* __restrict__ tprev_u32,
                 float* __restrict__ ws,
                 float* __restrict__ out) {
    __shared__ float sm[16];
    __shared__ float fsn[10];
    __shared__ int sflag;
    __shared__ int slast;
    const int bid = blockIdx.x;
    const int tid = threadIdx.x;
    const int lane = tid & 63;
    const int wv = tid >> 6;

    if (tid < 16) sm[tid] = 0.0f;

    // NLL blocks: detect int32 vs int64 layout of target_previous by probing
    // the first 64 odd dwords (high words if int64 layout -> all zero;
    // int32 layout -> values in [0,5), P(all zero) ~ 0.2^64 ~ 0).
    if (bid >= STAT_BLOCKS && wv == 0) {
        unsigned w = tprev_u32[2 * lane + 1];
        unsigned long long bal = __ballot(w != 0u);
        if (tid == 0) sflag = (bal != 0ull) ? 1 : 0;
    }
    __syncthreads();

    if (bid < STAT_BLOCKS) {
        // ---- per-batch stats over pred/target/points ----
        const int b = bid >> 6;
        const int chunk = bid & 63;
        const size_t n0 = (size_t)b * N_PTS + (size_t)chunk * 1024 + (size_t)tid * 4;

        const float4* __restrict__ p4 = (const float4*)(pred + n0 * 5);
        float4 q0 = p4[0], q1 = p4[1], q2 = p4[2], q3 = p4[3], q4 = p4[4];
        const int4 tg = *(const int4*)(target + n0);
        const float* __restrict__ pb = points + n0 * 9;
        float zv[4] = {pb[2], pb[11], pb[20], pb[29]};

        float xs[4][5] = {
            {q0.x, q0.y, q0.z, q0.w, q1.x},
            {q1.y, q1.z, q1.w, q2.x, q2.y},
            {q2.z, q2.w, q3.x, q3.y, q3.z},
            {q3.w, q4.x, q4.y, q4.z, q4.w}};
        int tgt[4] = {tg.x, tg.y, tg.z, tg.w};

        float gc0 = 0, gc1 = 0, gc2 = 0, gc3 = 0;
        float pc0 = 0, pc1 = 0, pc2 = 0, pc3 = 0;
        float gz0 = 0, gz1 = 0, gz2 = 0, gz3 = 0;
        float pz0 = 0, pz1 = 0, pz2 = 0, pz3 = 0;

#pragma unroll
        for (int j = 0; j < 4; ++j) {
            float x0 = xs[j][0], x1 = xs[j][1], x2 = xs[j][2],
                  x3 = xs[j][3], x4 = xs[j][4];
            int am = 0;
            float bv = x0;
            if (x1 > bv) { bv = x1; am = 1; }
            if (x2 > bv) { bv = x2; am = 2; }
            if (x3 > bv) { bv = x3; am = 3; }
            if (x4 > bv) { bv = x4; am = 4; }
            float z = zv[j];
            int t = tgt[j];
            if (t == 0) { gc0 += 1.f; gz0 += z; }
            else if (t == 1) { gc1 += 1.f; gz1 += z; }
            else if (t == 2) { gc2 += 1.f; gz2 += z; }
            else if (t == 3) { gc3 += 1.f; gz3 += z; }
            if (am == 0) { pc0 += 1.f; pz0 += z; }
            else if (am == 1) { pc1 += 1.f; pz1 += z; }
            else if (am == 2) { pc2 += 1.f; pz2 += z; }
            else if (am == 3) { pc3 += 1.f; pz3 += z; }
        }

        float vals[16] = {gc0, gc1, gc2, gc3, pc0, pc1, pc2, pc3,
                          gz0, gz1, gz2, gz3, pz0, pz1, pz2, pz3};
#pragma unroll
        for (int k = 0; k < 16; ++k) {
            float r = wave_reduce_f(vals[k]);
            if (lane == 0) atomicAdd(&sm[k], r);
        }
        __syncthreads();
        if (tid < 16) atomicAdd(&ws[b * 16 + tid], sm[tid]);
    } else {
        // ---- NLL + segment sums over pred_previous / target_previous ----
        const int nb = bid - STAT_BLOCKS;
        const size_t k0 = (size_t)nb * 1024 + (size_t)tid * 4;
        const int is32 = sflag;

        const float4* __restrict__ p4 = (const float4*)(prev + k0 * 5);
        float4 q0 = p4[0], q1 = p4[1], q2 = p4[2], q3 = p4[3], q4 = p4[4];

        int tgt[4];
        if (is32) {
            int4 tt = *(const int4*)((const int*)tprev_u32 + k0);
            tgt[0] = tt.x; tgt[1] = tt.y; tgt[2] = tt.z; tgt[3] = tt.w;
        } else {
            int4 a = *(const int4*)((const int*)tprev_u32 + 2 * k0);
            int4 c = *(const int4*)((const int*)tprev_u32 + 2 * k0 + 4);
            tgt[0] = a.x; tgt[1] = a.z; tgt[2] = c.x; tgt[3] = c.z;
        }

        float xs[4][5] = {
            {q0.x, q0.y, q0.z, q0.w, q1.x},
            {q1.y, q1.z, q1.w, q2.x, q2.y},
            {q2.z, q2.w, q3.x, q3.y, q3.z},
            {q3.w, q4.x, q4.y, q4.z, q4.w}};

        float s0 = 0, s1 = 0, s2 = 0, s3 = 0, s4 = 0;
        float c0 = 0, c1 = 0, c2 = 0, c3 = 0, c4 = 0;

        // x - m is in [-~12, 0] for normal(0,1) inputs: no overflow/underflow
        // edge cases, so native v_exp_f32 / v_log_f32 (__expf/__logf) are safe.
#pragma unroll
        for (int j = 0; j < 4; ++j) {
            float x0 = xs[j][0], x1 = xs[j][1], x2 = xs[j][2],
                  x3 = xs[j][3], x4 = xs[j][4];
            float m = fmaxf(fmaxf(fmaxf(x0, x1), fmaxf(x2, x3)), x4);
            float e = __expf(x0 - m) + __expf(x1 - m) + __expf(x2 - m) +
                      __expf(x3 - m) + __expf(x4 - m);
            float lse = m + __logf(e);
            int t = tgt[j];
            float xt = x0;
            xt = (t == 1) ? x1 : xt;
            xt = (t == 2) ? x2 : xt;
            xt = (t == 3) ? x3 : xt;
            xt = (t == 4) ? x4 : xt;
            float nll = lse - xt;
            if (t == 0) { s0 += nll; c0 += 1.f; }
            else if (t == 1) { s1 += nll; c1 += 1.f; }
            else if (t == 2) { s2 += nll; c2 += 1.f; }
            else if (t == 3) { s3 += nll; c3 += 1.f; }
            else { s4 += nll; c4 += 1.f; }
        }

        float vals[10] = {s0, s1, s2, s3, s4, c0, c1, c2, c3, c4};
#pragma unroll
        for (int k = 0; k < 10; ++k) {
            float r = wave_reduce_f(vals[k]);
            if (lane == 0) atomicAdd(&sm[k], r);
        }
        __syncthreads();
        if (tid < 10) atomicAdd(&ws[ACC_NLL + tid * 32 + (nb & 31)], sm[tid]);
    }

    // ---- last-block-done finalize (replaces separate final_kernel) ----
    __syncthreads();   // all global atomics of this block issued
    if (tid == 0) {
        __threadfence();
        int old = atomicAdd((int*)&ws[ACC_CNT], 1);
        slast = (old == GRID_BLOCKS - 1) ? 1 : 0;
    }
    __syncthreads();
    if (!slast) return;

    // Last block: every accumulator write is device-visible (atomics + fence +
    // counter ticket). These lines were never loaded by this block -> L1 clean.
    volatile const float* acc = ws;

    if (tid < 10) {
        float s = 0.0f;
#pragma unroll
        for (int k = 0; k < 32; ++k) s += acc[ACC_NLL + tid * 32 + k];
        fsn[tid] = s;
    }
    __syncthreads();

    float loss = 0.0f;
    if (tid < B_BATCH) {
        float gc[4], pc[4], gm[4], pm[4];
        bool GT[4], PR[4];
        float w[5] = {1.f, 1.f, 1.f, 1.f, 1.f};
#pragma unroll
        for (int c = 0; c < 4; ++c) {
            gc[c] = acc[tid * 16 + c];
            pc[c] = acc[tid * 16 + 4 + c];
            GT[c] = gc[c] > 0.0f;
            PR[c] = pc[c] > 0.0f;
            gm[c] = acc[tid * 16 + 8 + c] / fmaxf(gc[c], 1.0f);
            pm[c] = acc[tid * 16 + 12 + c] / fmaxf(pc[c], 1.0f);
            if (!GT[c] && PR[c]) w[c] += A_W;
        }
#define PAIR(i, j, mlt)                                                        \
        {                                                                      \
            bool cond = GT[i] && PR[i] && GT[j] && PR[j] &&                    \
                        (gm[i] < gm[j]) && (pm[i] >= pm[j]);                   \
            float add = (mlt) * A_W * (cond ? 1.0f : 0.0f);                    \
            w[i] += add;                                                       \
            w[j] += add;                                                       \
        }
        PAIR(0, 1, 1.0f)
        PAIR(1, 2, 1.0f)
        PAIR(2, 3, 1.0f)
        PAIR(0, 2, 2.0f)
        PAIR(1, 3, 2.0f)
        PAIR(0, 3, 3.0f)
#undef PAIR
        float num = 0.0f, den = 0.0f;
#pragma unroll
        for (int c = 0; c < C_CLS; ++c) {
            num += w[c] * fsn[c];
            den += w[c] * fsn[5 + c];
        }
        loss = num / den;
    }
    if (wv == 0) {
#pragma unroll
        for (int off = 8; off > 0; off >>= 1)
            loss += __shfl_down(loss, off, 64);
        if (tid == 0) out[0] = loss;
    }
}

extern "C" void kernel_launch(void* const* d_in, const int* in_sizes, int n_in,
                              void* d_out, int out_size, void* d_ws, size_t ws_size,
                              hipStream_t stream) {
    const float* pred = (const float*)d_in[0];
    const int* target = (const int*)d_in[1];
    const float* points = (const float*)d_in[2];
    const float* prev = (const float*)d_in[3];
    const unsigned* tprev = (const unsigned*)d_in[4];
    float* ws = (float*)d_ws;
    float* out = (float*)d_out;

    // Zero the accumulator + counter region (2.3 KB) — graph-capturable.
    hipMemsetAsync(ws, 0, ACC_BYTES, stream);
    hipLaunchKernelGGL(main_kernel, dim3(GRID_BLOCKS), dim3(TPB),
                       0, stream, pred, target, points, prev, tprev, ws, out);
}

// Round 3
// 113.063 us; speedup vs baseline: 1.6614x; 1.6614x over previous
//
#include <hip/hip_runtime.h>
#include <math.h>

#define A_W 200.0f
#define B_BATCH 16
#define N_PTS 65536
#define C_CLS 5
#define BN (B_BATCH * N_PTS)

#define STAT_BLOCKS 1024   // 64 blocks per batch, 1024 points each, 4 pts/thread
#define NLL_BLOCKS 1024    // 1024 elements each, 4 elems/thread
#define TPB 256
#define NLL_BASE 16384     // float offset in ws for NLL partials

// ws layout (floats):
//  [0 .. 16383]              stat partials: block bid writes 16 floats at bid*16
//                            order: gc0..3, pc0..3, gz0..3, pz0..3
//  [16384 .. 16384+10239]    NLL partials, transposed: value v at NLL_BASE + v*1024 + nb
//                            v: 0..4 = nll sums s0..s4, 5..9 = counts c0..c4

__device__ inline float wave_reduce_f(float v) {
#pragma unroll
    for (int off = 32; off > 0; off >>= 1)
        v += __shfl_down(v, off, 64);
    return v;
}

__global__ __launch_bounds__(TPB)
void main_kernel(const float* __restrict__ pred,
                 const int* __restrict__ target,
                 const float* __restrict__ points,
                 const float* __restrict__ prev,
                 const unsigned* __restrict__ tprev_u32,
                 float* __restrict__ ws) {
    __shared__ float sm[16];
    __shared__ int sflag;
    const int bid = blockIdx.x;
    const int tid = threadIdx.x;
    const int lane = tid & 63;
    const int wv = tid >> 6;

    if (tid < 16) sm[tid] = 0.0f;

    // NLL blocks: detect int32 vs int64 layout of target_previous by probing
    // the first 64 odd dwords (high words if int64 layout -> all zero;
    // int32 layout -> values in [0,5), P(all zero) ~ 0.2^64 ~ 0).
    // First 512 B is in-bounds for both layouts; all blocks hit same L2 lines.
    if (bid >= STAT_BLOCKS && wv == 0) {
        unsigned w = tprev_u32[2 * lane + 1];
        unsigned long long bal = __ballot(w != 0u);
        if (tid == 0) sflag = (bal != 0ull) ? 1 : 0;
    }
    __syncthreads();

    if (bid < STAT_BLOCKS) {
        // ---- per-batch stats over pred/target/points ----
        const int b = bid >> 6;
        const int chunk = bid & 63;
        const size_t n0 = (size_t)b * N_PTS + (size_t)chunk * 1024 + (size_t)tid * 4;

        const float4* __restrict__ p4 = (const float4*)(pred + n0 * 5);
        float4 q0 = p4[0], q1 = p4[1], q2 = p4[2], q3 = p4[3], q4 = p4[4];
        const int4 tg = *(const int4*)(target + n0);
        const float* __restrict__ pb = points + n0 * 9;
        float zv[4] = {pb[2], pb[11], pb[20], pb[29]};

        float xs[4][5] = {
            {q0.x, q0.y, q0.z, q0.w, q1.x},
            {q1.y, q1.z, q1.w, q2.x, q2.y},
            {q2.z, q2.w, q3.x, q3.y, q3.z},
            {q3.w, q4.x, q4.y, q4.z, q4.w}};
        int tgt[4] = {tg.x, tg.y, tg.z, tg.w};

        float gc0 = 0, gc1 = 0, gc2 = 0, gc3 = 0;
        float pc0 = 0, pc1 = 0, pc2 = 0, pc3 = 0;
        float gz0 = 0, gz1 = 0, gz2 = 0, gz3 = 0;
        float pz0 = 0, pz1 = 0, pz2 = 0, pz3 = 0;

#pragma unroll
        for (int j = 0; j < 4; ++j) {
            float x0 = xs[j][0], x1 = xs[j][1], x2 = xs[j][2],
                  x3 = xs[j][3], x4 = xs[j][4];
            int am = 0;
            float bv = x0;
            if (x1 > bv) { bv = x1; am = 1; }
            if (x2 > bv) { bv = x2; am = 2; }
            if (x3 > bv) { bv = x3; am = 3; }
            if (x4 > bv) { bv = x4; am = 4; }
            float z = zv[j];
            int t = tgt[j];
            if (t == 0) { gc0 += 1.f; gz0 += z; }
            else if (t == 1) { gc1 += 1.f; gz1 += z; }
            else if (t == 2) { gc2 += 1.f; gz2 += z; }
            else if (t == 3) { gc3 += 1.f; gz3 += z; }
            if (am == 0) { pc0 += 1.f; pz0 += z; }
            else if (am == 1) { pc1 += 1.f; pz1 += z; }
            else if (am == 2) { pc2 += 1.f; pz2 += z; }
            else if (am == 3) { pc3 += 1.f; pz3 += z; }
        }

        float vals[16] = {gc0, gc1, gc2, gc3, pc0, pc1, pc2, pc3,
                          gz0, gz1, gz2, gz3, pz0, pz1, pz2, pz3};
#pragma unroll
        for (int k = 0; k < 16; ++k) {
            float r = wave_reduce_f(vals[k]);
            if (lane == 0) atomicAdd(&sm[k], r);
        }
        __syncthreads();
        if (tid < 16) ws[(size_t)bid * 16 + tid] = sm[tid];
    } else {
        // ---- NLL + segment sums over pred_previous / target_previous ----
        const int nb = bid - STAT_BLOCKS;
        const size_t k0 = (size_t)nb * 1024 + (size_t)tid * 4;
        const int is32 = sflag;

        const float4* __restrict__ p4 = (const float4*)(prev + k0 * 5);
        float4 q0 = p4[0], q1 = p4[1], q2 = p4[2], q3 = p4[3], q4 = p4[4];

        int tgt[4];
        if (is32) {
            int4 tt = *(const int4*)((const int*)tprev_u32 + k0);
            tgt[0] = tt.x; tgt[1] = tt.y; tgt[2] = tt.z; tgt[3] = tt.w;
        } else {
            int4 a = *(const int4*)((const int*)tprev_u32 + 2 * k0);
            int4 c = *(const int4*)((const int*)tprev_u32 + 2 * k0 + 4);
            tgt[0] = a.x; tgt[1] = a.z; tgt[2] = c.x; tgt[3] = c.z;
        }

        float xs[4][5] = {
            {q0.x, q0.y, q0.z, q0.w, q1.x},
            {q1.y, q1.z, q1.w, q2.x, q2.y},
            {q2.z, q2.w, q3.x, q3.y, q3.z},
            {q3.w, q4.x, q4.y, q4.z, q4.w}};

        float s0 = 0, s1 = 0, s2 = 0, s3 = 0, s4 = 0;
        float c0 = 0, c1 = 0, c2 = 0, c3 = 0, c4 = 0;

        // x - m is in [-~12, 0] for normal(0,1) inputs: no overflow/underflow
        // edge cases, so native v_exp_f32 / v_log_f32 (__expf/__logf) are safe.
#pragma unroll
        for (int j = 0; j < 4; ++j) {
            float x0 = xs[j][0], x1 = xs[j][1], x2 = xs[j][2],
                  x3 = xs[j][3], x4 = xs[j][4];
            float m = fmaxf(fmaxf(fmaxf(x0, x1), fmaxf(x2, x3)), x4);
            float e = __expf(x0 - m) + __expf(x1 - m) + __expf(x2 - m) +
                      __expf(x3 - m) + __expf(x4 - m);
            float lse = m + __logf(e);
            int t = tgt[j];
            float xt = x0;
            xt = (t == 1) ? x1 : xt;
            xt = (t == 2) ? x2 : xt;
            xt = (t == 3) ? x3 : xt;
            xt = (t == 4) ? x4 : xt;
            float nll = lse - xt;
            if (t == 0) { s0 += nll; c0 += 1.f; }
            else if (t == 1) { s1 += nll; c1 += 1.f; }
            else if (t == 2) { s2 += nll; c2 += 1.f; }
            else if (t == 3) { s3 += nll; c3 += 1.f; }
            else { s4 += nll; c4 += 1.f; }
        }

        float vals[10] = {s0, s1, s2, s3, s4, c0, c1, c2, c3, c4};
#pragma unroll
        for (int k = 0; k < 10; ++k) {
            float r = wave_reduce_f(vals[k]);
            if (lane == 0) atomicAdd(&sm[k], r);
        }
        __syncthreads();
        if (tid < 10) ws[NLL_BASE + (size_t)tid * 1024 + nb] = sm[tid];
    }
}

__global__ __launch_bounds__(1024)
void final_kernel(const float* __restrict__ ws, float* __restrict__ out) {
    __shared__ float stat[256];
    __shared__ float sn[10];
    const int t = threadIdx.x;
    const int lane = t & 63;
    const int wv = t >> 6;

    // ---- stat partial reduction: one wave per batch, coalesced ----
    // Batch w's 1024 partials are contiguous at ws[w*1024 ..]; position
    // p = chunk*16 + v, and p = lane + 64*k  =>  v = lane & 15 (64k == 0 mod 16).
    // Lane sums its 16 stride-64 elements (coalesced 256B/wave per k), then
    // shfl_xor 16,32 folds the 4 lane-groups sharing (lane&15).
    {
        const int b = wv;  // 16 waves, 16 batches
        const float* p = ws + (size_t)b * 1024;
        float s = 0.0f;
#pragma unroll
        for (int k = 0; k < 16; ++k) s += p[lane + 64 * k];
        s += __shfl_xor(s, 16, 64);
        s += __shfl_xor(s, 32, 64);
        if (lane < 16) stat[b * 16 + lane] = s;
    }
    // ---- NLL partial reduction: waves 0..9, value v = wave ----
    if (wv < 10) {
        const float* p = ws + NLL_BASE + (size_t)wv * 1024;
        float s = 0.0f;
#pragma unroll
        for (int k = 0; k < 16; ++k) s += p[lane + 64 * k];
        s = wave_reduce_f(s);
        if (lane == 0) sn[wv] = s;
    }
    __syncthreads();

    float loss = 0.0f;
    if (t < B_BATCH) {
        const float* st = stat + t * 16;
        float gc[4], pc[4], gm[4], pm[4];
        bool GT[4], PR[4];
        float w[5] = {1.f, 1.f, 1.f, 1.f, 1.f};
#pragma unroll
        for (int c = 0; c < 4; ++c) {
            gc[c] = st[c];
            pc[c] = st[4 + c];
            GT[c] = gc[c] > 0.0f;
            PR[c] = pc[c] > 0.0f;
            gm[c] = st[8 + c] / fmaxf(gc[c], 1.0f);
            pm[c] = st[12 + c] / fmaxf(pc[c], 1.0f);
            if (!GT[c] && PR[c]) w[c] += A_W;
        }
#define PAIR(i, j, mlt)                                                        \
        {                                                                      \
            bool cond = GT[i] && PR[i] && GT[j] && PR[j] &&                    \
                        (gm[i] < gm[j]) && (pm[i] >= pm[j]);                   \
            float add = (mlt) * A_W * (cond ? 1.0f : 0.0f);                    \
            w[i] += add;                                                       \
            w[j] += add;                                                       \
        }
        PAIR(0, 1, 1.0f)
        PAIR(1, 2, 1.0f)
        PAIR(2, 3, 1.0f)
        PAIR(0, 2, 2.0f)
        PAIR(1, 3, 2.0f)
        PAIR(0, 3, 3.0f)
#undef PAIR
        float num = 0.0f, den = 0.0f;
#pragma unroll
        for (int c = 0; c < C_CLS; ++c) {
            num += w[c] * sn[c];
            den += w[c] * sn[5 + c];
        }
        loss = num / den;
    }
    if (wv == 0) {
#pragma unroll
        for (int off = 8; off > 0; off >>= 1)
            loss += __shfl_down(loss, off, 64);
        if (t == 0) out[0] = loss;
    }
}

extern "C" void kernel_launch(void* const* d_in, const int* in_sizes, int n_in,
                              void* d_out, int out_size, void* d_ws, size_t ws_size,
                              hipStream_t stream) {
    const float* pred = (const float*)d_in[0];
    const int* target = (const int*)d_in[1];
    const float* points = (const float*)d_in[2];
    const float* prev = (const float*)d_in[3];
    const unsigned* tprev = (const unsigned*)d_in[4];
    float* ws = (float*)d_ws;
    float* out = (float*)d_out;

    hipLaunchKernelGGL(main_kernel, dim3(STAT_BLOCKS + NLL_BLOCKS), dim3(TPB),
                       0, stream, pred, target, points, prev, tprev, ws);
    hipLaunchKernelGGL(final_kernel, dim3(1), dim3(1024), 0, stream, ws, out);
}